// Round 1
// baseline (141.212 us; speedup 1.0000x reference)
//
#include <hip/hip_runtime.h>

// Reference semantics are fp32 sign tests on shape boundary functions; the
// output is a discrete color choice, so predicates must match numpy's fp32
// rounding bit-exactly. Disable FMA contraction globally (hipcc defaults to
// -ffp-contract=fast which would perturb last-ulp signs on edge functions).
#pragma clang fp contract(off)

#define NPTS 2097152

// d_ws float layout (needs 4000 bytes):
//   triC : [25][16]  ax,ay,bx,by,cx,cy, (by-ay),(bx-ax), (cy-by),(cx-bx), (ay-cy),(ax-cx), pad*4
//   circC: [25][4]   ocx,ocy,orr*orr,pad
//   ellC : [25][8]   ecx,ecy,erx,ery, 1/erx, 1/ery, pad,pad
//   col  : [75][4]   r,g,b,pad   (shape index 3c+{0,1,2} = tri,circ,ell)
#define TRI_OFF   0
#define CIRC_OFF  (25 * 16)            // 400
#define ELL_OFF   (CIRC_OFF + 25 * 4)  // 500
#define COL_OFF   (ELL_OFF + 25 * 8)   // 700
// total 1000 floats

__global__ void vg_precompute(const float* __restrict__ p, float* __restrict__ ws) {
    int t = threadIdx.x;
    if (t < 25) {
        const float* cell = p + t * 28;
        float ax = cell[1], ay = cell[2], bx = cell[3], by = cell[4], cx = cell[5], cy = cell[6];
        float* o = ws + TRI_OFF + t * 16;
        o[0] = ax; o[1] = ay; o[2] = bx; o[3] = by; o[4] = cx; o[5] = cy;
        o[6]  = by - ay; o[7]  = bx - ax;   // edge0
        o[8]  = cy - by; o[9]  = cx - bx;   // edge1
        o[10] = ay - cy; o[11] = ax - cx;   // edge2
        o[12] = 0.f; o[13] = 0.f; o[14] = 0.f; o[15] = 0.f;
        float* col = ws + COL_OFF + (3 * t + 0) * 4;
        col[0] = cell[8]; col[1] = cell[9]; col[2] = cell[10]; col[3] = 0.f;
    } else if (t < 50) {
        int c = t - 25;
        const float* cell = p + c * 28;
        float ocx = cell[12], ocy = cell[13], orr = cell[14];
        float* o = ws + CIRC_OFF + c * 4;
        o[0] = ocx; o[1] = ocy; o[2] = orr * orr; o[3] = 0.f;  // orr**2: same rounding as numpy
        float* col = ws + COL_OFF + (3 * c + 1) * 4;
        col[0] = cell[16]; col[1] = cell[17]; col[2] = cell[18]; col[3] = 0.f;
    } else if (t < 75) {
        int c = t - 50;
        const float* cell = p + c * 28;
        float ecx = cell[20], ecy = cell[21], erx = cell[22], ery = cell[23];
        float* o = ws + ELL_OFF + c * 8;
        o[0] = ecx; o[1] = ecy; o[2] = erx; o[3] = ery;
        o[4] = 1.0f / erx;  // approx-filter reciprocals (exact path divides for real)
        o[5] = 1.0f / ery;
        o[6] = 0.f; o[7] = 0.f;
        float* col = ws + COL_OFF + (3 * c + 2) * 4;
        col[0] = cell[25]; col[1] = cell[26]; col[2] = cell[27]; col[3] = 0.f;
    }
}

__global__ __launch_bounds__(256) void vg_main(const float* __restrict__ x,
                                               const float* __restrict__ ws,
                                               float* __restrict__ out) {
    int i = blockIdx.x * 256 + threadIdx.x;
    if (i >= NPTS) return;
    float px = x[2 * i + 0];
    float py = x[2 * i + 1];

    int idx = -1;  // last shape containing the point

    #pragma unroll
    for (int c = 0; c < 25; ++c) {
        // ---- triangle (shape 3c) — exact numpy fp32 order ----
        const float* tc = ws + TRI_OFF + c * 16;
        float e0 = (px - tc[0]) * tc[6]  - (py - tc[1]) * tc[7];
        float e1 = (px - tc[2]) * tc[8]  - (py - tc[3]) * tc[9];
        float e2 = (px - tc[4]) * tc[10] - (py - tc[5]) * tc[11];
        float lo = fminf(fminf(e0, e1), e2);
        float hi = fmaxf(fmaxf(e0, e1), e2);
        bool tri_in = (lo >= 0.0f) || (hi <= 0.0f);
        idx = tri_in ? (3 * c + 0) : idx;

        // ---- circle (shape 3c+1) — exact ----
        const float* cc = ws + CIRC_OFF + c * 4;
        float dx = px - cc[0];
        float dy = py - cc[1];
        bool circ_in = (dx * dx + dy * dy) <= cc[2];
        idx = circ_in ? (3 * c + 1) : idx;

        // ---- ellipse (shape 3c+2) — approx filter + rare exact-divide fallback ----
        const float* ec = ws + ELL_OFF + c * 8;
        float ex = px - ec[0];
        float ey = py - ec[1];
        float ua = ex * ec[4];
        float va = ey * ec[5];
        float t  = ua * ua + va * va;          // rel err <= ~1e-6 vs exact
        bool ell_in = t <= 1.0f;
        if (__builtin_fabsf(t - 1.0f) < 1e-5f) {
            // exact numpy path: ((ex/erx)**2 + (ey/ery)**2) <= 1, IEEE division
            float u = ex / ec[2];
            float v = ey / ec[3];
            float u2 = u * u;
            float v2 = v * v;
            ell_in = (u2 + v2) <= 1.0f;
        }
        idx = ell_in ? (3 * c + 2) : idx;
    }

    int ci = idx < 0 ? 0 : idx;
    const float* col = ws + COL_OFF + ci * 4;
    float r = col[0], g = col[1], b = col[2];
    if (idx < 0) { r = 0.0f; g = 0.0f; b = 0.0f; }
    out[3 * i + 0] = r;
    out[3 * i + 1] = g;
    out[3 * i + 2] = b;
}

extern "C" void kernel_launch(void* const* d_in, const int* in_sizes, int n_in,
                              void* d_out, int out_size, void* d_ws, size_t ws_size,
                              hipStream_t stream) {
    const float* x = (const float*)d_in[0];   // (NPTS, 2) fp32
    const float* p = (const float*)d_in[1];   // (700,)   fp32
    float* out = (float*)d_out;               // (NPTS, 3) fp32
    float* ws  = (float*)d_ws;                // >= 4000 bytes

    vg_precompute<<<1, 128, 0, stream>>>(p, ws);
    vg_main<<<NPTS / 256, 256, 0, stream>>>(x, ws, out);
}